// Round 8
// baseline (745.623 us; speedup 1.0000x reference)
//
#include <hip/hip_runtime.h>
#include <hip/hip_bf16.h>
#include <cstdint>

#define B_ 8
#define S_ 2048
#define E_ 1024

using u16 = unsigned short;

typedef __bf16 bf16x8 __attribute__((ext_vector_type(8)));
typedef float f32x4 __attribute__((ext_vector_type(4)));

__device__ inline u16 f2bf(float f) {
  uint32_t u = __float_as_uint(f);
  uint32_t r = (u + 0x7fffu + ((u >> 16) & 1u)) >> 16;
  return (u16)r;
}

// ---------------------------------------------------------------------------
// NT GEMM, r8: OCCUPANCY build. 128x128 tile, BK=32, 256 threads (4 waves
// 2x2, 64x64/wave), SINGLE-buffer 16KB LDS, __launch_bounds__(256,4) forcing
// <=128 unified regs/wave -> 16 waves/CU (4 blocks co-resident).
// Rationale: r0-r7 all ran 2 waves/SIMD (>128 regs incl. AGPR -> 8-wave/CU
// bucket, m69) and pinned at ~740TF regardless of schedule; m97 hit 874-912TF
// with a SIMPLE drain loop at 12 waves/CU — cross-block co-scheduling (m114)
// is the lever, not in-block scheduling.
// Per K-tile: 8 asm ds_read_b128 | counted lgkm(3/2/1/0) into 4 MFMA groups
// (setprio) | BAR (reads done chip-wide) | STAGE(t+1) overwrite | vmcnt(0)
// | BAR. Stage-latency exposure is covered by 3 sibling blocks.
// Swizzle (64B rows, 4x16B chunks): chunk ^= (row&3)^((row>>2)&1) — rows 0-7
// map to 8 distinct bank-quads (2-way across 16 lanes = free, m136); global
// SOURCE column pre-swizzled with the same involution (both-sides rule).
// ---------------------------------------------------------------------------
template<bool HAS_BIAS, bool RELU, bool HAS_RES, bool OUT_BF16, bool SCORES,
         bool GATHER_A, bool RUNTK>
__global__ __launch_bounds__(256, 4) void gemm_nt(
    const u16* __restrict__ A, const u16* __restrict__ B, void* __restrict__ C,
    const float* __restrict__ bias, const float* __restrict__ res,
    int lda, int ldb, int ldc, int K,
    long long strideA, long long strideB, long long strideC,
    const int* __restrict__ cidx, const int* __restrict__ cnt)
{
  __shared__ __attribute__((aligned(16))) u16 lA[128 * 32];
  __shared__ __attribute__((aligned(16))) u16 lB[128 * 32];

  const int tid  = threadIdx.x;
  const int lane = tid & 63;
  const int wave = tid >> 6;             // 0..3

  // ---- XCD-compacting block swizzle ----
  const int GM = 8, GN = 4;
  const int nbn = gridDim.x, nbm = gridDim.y, nz = gridDim.z;
  int bm, bn, bz;
  {
    const int total = nbn * nbm * nz;
    const long long lin = blockIdx.x +
        (long long)nbn * (blockIdx.y + (long long)nbm * blockIdx.z);
    if ((nbm % GM) == 0 && (nbn % GN) == 0 && (total % (8 * GM * GN)) == 0) {
      const int xcd = (int)(lin & 7);
      const int loc = (int)(lin >> 3);
      const int sper = GM * GN;
      const int super = (loc / sper) * 8 + xcd;
      const int ins   = loc % sper;
      const int spz = (nbm / GM) * (nbn / GN);
      bz = super / spz;
      const int s2 = super % spz;
      const int sm = s2 % (nbm / GM);
      const int sn = s2 / (nbm / GM);
      bm = sm * GM + (ins % GM);
      bn = sn * GN + (ins / GM);
    } else { bm = blockIdx.y; bn = blockIdx.x; bz = blockIdx.z; }
  }

  int count = 0, cpad = 0;
  if (SCORES || GATHER_A || RUNTK) {
    count = cnt[bz * 2];
    cpad  = cnt[bz * 2 + 1];               // 128-aligned
    if (GATHER_A && bm * 128 >= cpad) return;   // block-uniform, pre-barrier
    if (SCORES   && bn * 128 >= cpad) return;
  }
  const int Keff = RUNTK ? cpad : K;
  const int nk = Keff >> 5;                // K-tiles of 32 (>= 4 always)

  const u16* Ab = A + (long long)bz * strideA;
  const u16* Bb = B + (long long)bz * strideB;

  // ---- staging addresses (per thread: 2x16B A + 2x16B B per K-tile) ----
  const int srow = tid >> 2;               // 0..63 (+l*64)
  // inverse-swizzled SOURCE chunk; (srow+l*64) keeps (&3) and (>>2)&1 parity
  const int scol = ((tid & 3) ^ (srow & 3) ^ ((srow >> 2) & 1)) * 8;
  long long rowA[2], rowB[2];
#pragma unroll
  for (int l = 0; l < 2; ++l) {
    int ra = bm * 128 + srow + l * 64;
    if (GATHER_A) ra = cidx[(long long)bz * S_ + ra];
    rowA[l] = (long long)ra * lda + scol;
    rowB[l] = (long long)(bn * 128 + srow + l * 64) * ldb + scol;
  }
  const int ldsoff = tid * 8;              // elems within a 2048-elem half

  // ---- fragment read addresses (swizzled, 32-bit LDS offsets for asm) ----
  const int wr = wave >> 1, wc = wave & 1;
  const int rA = wr * 64 + (lane & 15);    // +mi*16 (swizzle bits invariant)
  const int rB = wc * 64 + (lane & 15);    // +ni*16
#define LDSP3(P) ((uint32_t)(uintptr_t)(__attribute__((address_space(3))) const void*)(P))
  const uint32_t aA = LDSP3(&lA[0]) +
      2u * (uint32_t)(rA * 32 + (((lane >> 4) ^ (rA & 3) ^ ((rA >> 2) & 1)) * 8));
  const uint32_t bB = LDSP3(&lB[0]) +
      2u * (uint32_t)(rB * 32 + (((lane >> 4) ^ (rB & 3) ^ ((rB >> 2) & 1)) * 8));
#undef LDSP3

  f32x4 acc[4][4];                         // [mi][ni]
#pragma unroll
  for (int mi = 0; mi < 4; ++mi)
#pragma unroll
    for (int ni = 0; ni < 4; ++ni)
      acc[mi][ni] = (f32x4){0.f, 0.f, 0.f, 0.f};

#define STAGE(T) {                                                             \
    const int tt_ = ((T) < nk) ? (T) : (nk - 1);                               \
    _Pragma("unroll") for (int l = 0; l < 2; ++l)                              \
      __builtin_amdgcn_global_load_lds(                                        \
          (const __attribute__((address_space(1))) void*)                      \
              (Ab + rowA[l] + (long long)tt_ * 32),                            \
          (__attribute__((address_space(3))) void*)                            \
              (&lA[l * 2048 + ldsoff]),                                        \
          16, 0, 0);                                                           \
    _Pragma("unroll") for (int l = 0; l < 2; ++l)                              \
      __builtin_amdgcn_global_load_lds(                                        \
          (const __attribute__((address_space(1))) void*)                      \
              (Bb + rowB[l] + (long long)tt_ * 32),                            \
          (__attribute__((address_space(3))) void*)                            \
              (&lB[l * 2048 + ldsoff]),                                        \
          16, 0, 0); }

#define DSR(D, ADDR, OFF) \
    asm volatile("ds_read_b128 %0, %1 offset:" OFF : "=v"(D) : "v"(ADDR))
#define LGKM(NSTR) asm volatile("s_waitcnt lgkmcnt(" NSTR ")" ::: "memory")
#define SCHED0()   __builtin_amdgcn_sched_barrier(0)
#define BAR()      __builtin_amdgcn_s_barrier()

// 4 MFMAs for one ni column (all mi)
#define MFMA_NI(NI) {                                                          \
    _Pragma("unroll") for (int mi = 0; mi < 4; ++mi)                           \
        acc[mi][NI] = __builtin_amdgcn_mfma_f32_16x16x32_bf16(                 \
            af[mi], bf[NI], acc[mi][NI], 0, 0, 0); }

  // ---- prologue: stage tile0; drain; barrier ----
  STAGE(0);
  asm volatile("s_waitcnt vmcnt(0)" ::: "memory");
  BAR();

  bf16x8 af[4], bf[4];
  for (int t = 0; t < nk; ++t) {
    // 8 asm reads: A rows first, then B
    DSR(af[0], aA, "0");     DSR(af[1], aA, "1024");
    DSR(af[2], aA, "2048");  DSR(af[3], aA, "3072");
    DSR(bf[0], bB, "0");     DSR(bf[1], bB, "1024");
    DSR(bf[2], bB, "2048");  DSR(bf[3], bB, "3072");
    __builtin_amdgcn_s_setprio(1);
    LGKM("3"); SCHED0(); MFMA_NI(0);
    LGKM("2"); SCHED0(); MFMA_NI(1);
    LGKM("1"); SCHED0(); MFMA_NI(2);
    LGKM("0"); SCHED0(); MFMA_NI(3);
    __builtin_amdgcn_s_setprio(0);
    BAR();                                 // all waves' reads complete
    STAGE(t + 1);                          // overwrite safe (dummy at tail)
    asm volatile("s_waitcnt vmcnt(0)" ::: "memory");
    BAR();
  }

#undef MFMA_NI
#undef DSR
#undef STAGE
#undef BAR
#undef LGKM
#undef SCHED0

  // ---- epilogue: C/D layout col = lane&15, row = (lane>>4)*4 + reg ----
  const float* resb = (const float*)C;
  if (HAS_RES) resb = res + (long long)bz * strideC;
  u16*   cb16 = (u16*)C   + (long long)bz * strideC;
  float* cf32 = (float*)C + (long long)bz * strideC;

#pragma unroll
  for (int ni = 0; ni < 4; ++ni) {
    const int gn = bn * 128 + wc * 64 + ni * 16 + (lane & 15);
    const float bvv = HAS_BIAS ? bias[gn] : 0.f;
    const bool cmask = SCORES && (gn >= count);
#pragma unroll
    for (int mi = 0; mi < 4; ++mi) {
#pragma unroll
      for (int r = 0; r < 4; ++r) {
        const int gm = bm * 128 + wr * 64 + mi * 16 + (lane >> 4) * 4 + r;
        const long long idx = (long long)gm * ldc + gn;
        float v = acc[mi][ni][r] + bvv;
        if (SCORES) { v *= 0.03125f; if (cmask) v = -3.0e38f; }
        if (RELU) v = fmaxf(v, 0.f);
        if (HAS_RES) v += resb[idx];
        if (OUT_BF16) cb16[idx] = f2bf(v);
        else          cf32[idx] = v;
      }
    }
  }
}

// ---------------------------------------------------------------------------
__global__ __launch_bounds__(256) void layernorm_kernel(
    const float* __restrict__ x, const float* __restrict__ w,
    const float* __restrict__ b, u16* __restrict__ out)
{
  const int row = blockIdx.x;
  const int tid = threadIdx.x;
  const float4 v = ((const float4*)(x + (long long)row * E_))[tid];
  float s  = v.x + v.y + v.z + v.w;
  float s2 = v.x * v.x + v.y * v.y + v.z * v.z + v.w * v.w;
#pragma unroll
  for (int o = 32; o >= 1; o >>= 1) { s += __shfl_xor(s, o); s2 += __shfl_xor(s2, o); }
  __shared__ float rs[4], rs2[4];
  const int wave = tid >> 6, lane = tid & 63;
  if (lane == 0) { rs[wave] = s; rs2[wave] = s2; }
  __syncthreads();
  s  = rs[0] + rs[1] + rs[2] + rs[3];
  s2 = rs2[0] + rs2[1] + rs2[2] + rs2[3];
  const float mu   = s * (1.f / E_);
  const float var  = s2 * (1.f / E_) - mu * mu;
  const float rstd = rsqrtf(var + 1e-5f);
  const float4 wv = ((const float4*)w)[tid];
  const float4 bv = ((const float4*)b)[tid];
  ushort4 o;
  o.x = f2bf((v.x - mu) * rstd * wv.x + bv.x);
  o.y = f2bf((v.y - mu) * rstd * wv.y + bv.y);
  o.z = f2bf((v.z - mu) * rstd * wv.z + bv.z);
  o.w = f2bf((v.w - mu) * rstd * wv.w + bv.w);
  ((ushort4*)(out + (long long)row * E_))[tid] = o;
}

// ---------------------------------------------------------------------------
// in-place softmax over one bf16 row; only cols < cnt_pad touched
__global__ __launch_bounds__(256) void softmax_bf16_kernel(
    u16* __restrict__ sp, const int* __restrict__ cnt)
{
  const int row = blockIdx.x;
  const int bz  = row >> 11;            // row / S_
  const int tid = threadIdx.x;
  const int cpad = cnt[bz * 2 + 1];
  const bool act = (tid * 8) < cpad;
  u16* pr = sp + (long long)row * S_;

  float v[8];
  if (act) {
    const uint4 raw = ((const uint4*)pr)[tid];
    const uint32_t w[4] = {raw.x, raw.y, raw.z, raw.w};
#pragma unroll
    for (int c = 0; c < 4; ++c) {
      v[2 * c]     = __uint_as_float(w[c] << 16);
      v[2 * c + 1] = __uint_as_float(w[c] & 0xffff0000u);
    }
  } else {
#pragma unroll
    for (int i = 0; i < 8; ++i) v[i] = -3.38e38f;
  }
  float mx = -3.38e38f;
#pragma unroll
  for (int i = 0; i < 8; ++i) mx = fmaxf(mx, v[i]);
#pragma unroll
  for (int o = 32; o >= 1; o >>= 1) mx = fmaxf(mx, __shfl_xor(mx, o));
  __shared__ float red[4];
  const int wave = tid >> 6, lane = tid & 63;
  if (lane == 0) red[wave] = mx;
  __syncthreads();
  mx = fmaxf(fmaxf(red[0], red[1]), fmaxf(red[2], red[3]));

  float s = 0.f;
#pragma unroll
  for (int i = 0; i < 8; ++i) { v[i] = __expf(v[i] - mx); s += v[i]; }
#pragma unroll
  for (int o = 32; o >= 1; o >>= 1) s += __shfl_xor(s, o);
  __syncthreads();
  if (lane == 0) red[wave] = s;
  __syncthreads();
  s = red[0] + red[1] + red[2] + red[3];
  const float inv = 1.f / s;

  if (act) {
    uint4 o4;
    uint32_t* ow = (uint32_t*)&o4;
#pragma unroll
    for (int c = 0; c < 4; ++c) {
      const uint32_t lo = f2bf(v[2 * c] * inv);
      const uint32_t hi = f2bf(v[2 * c + 1] * inv);
      ow[c] = lo | (hi << 16);
    }
    ((uint4*)pr)[tid] = o4;
  }
}

// ---------------------------------------------------------------------------
// V slice of KVc [bc][S_,2E] (cols [E,2E)) -> Vt [bc][E][S_], early-out > cpad
__global__ __launch_bounds__(256) void transpose_kernel(
    const u16* __restrict__ KVc, u16* __restrict__ Vt, const int* __restrict__ cnt)
{
  const int bl = blockIdx.z;
  const int s0 = blockIdx.y * 32;
  if (s0 >= cnt[bl * 2 + 1]) return;
  __shared__ u16 tile[32][33];
  const int e0 = blockIdx.x * 32;
  const int tx = threadIdx.x & 31, ty = threadIdx.x >> 5;   // ty 0..7
  const u16* src = KVc + ((long long)bl * S_ + s0) * (2 * E_) + E_ + e0;
#pragma unroll
  for (int r = 0; r < 32; r += 8)
    tile[ty + r][tx] = src[(long long)(ty + r) * (2 * E_) + tx];
  __syncthreads();
  u16* dst = Vt + ((long long)bl * E_ + e0) * S_ + s0;
#pragma unroll
  for (int r = 0; r < 32; r += 8)
    dst[(long long)(ty + r) * S_ + tx] = tile[tx][ty + r];
}

// ---------------------------------------------------------------------------
// fused weight converts + bias concat
__global__ __launch_bounds__(256) void prep_kernel(
    const float* __restrict__ Wq, const float* __restrict__ Wk,
    const float* __restrict__ Wv, const float* __restrict__ W1,
    const float* __restrict__ W2, const float* __restrict__ bk,
    const float* __restrict__ bv,
    u16* __restrict__ Wqb, u16* __restrict__ Wkvb,
    u16* __restrict__ W1b, u16* __restrict__ W2b, float* __restrict__ bkv)
{
  const int N1 = E_ * E_;
  const long long i = (long long)blockIdx.x * 256 + threadIdx.x;
  if (i < N1)               Wqb[i] = f2bf(Wq[i]);
  else if (i < 2LL * N1)    Wkvb[i - N1] = f2bf(Wk[i - N1]);
  else if (i < 3LL * N1)    Wkvb[N1 + (i - 2LL * N1)] = f2bf(Wv[i - 2LL * N1]);
  else if (i < 5LL * N1)    W1b[i - 3LL * N1] = f2bf(W1[i - 3LL * N1]);
  else if (i < 7LL * N1)    W2b[i - 5LL * N1] = f2bf(W2[i - 5LL * N1]);
  else if (i < 7LL * N1 + 2 * E_) {
    const int j = (int)(i - 7LL * N1);
    bkv[j] = (j < E_) ? bk[j] : bv[j - E_];
  }
}

// Detect pad_mask storage: int32 0/1 has zero bytes at i%4!=0; u8 does not.
__global__ void detect_kernel(const unsigned char* __restrict__ m, int* __restrict__ flag)
{
  __shared__ int any;
  if (threadIdx.x == 0) any = 0;
  __syncthreads();
  int loc = 0;
  for (int i = threadIdx.x; i < B_ * S_; i += 256)
    if ((i & 3) && m[i]) loc = 1;
  if (loc) atomicOr(&any, 1);
  __syncthreads();
  if (threadIdx.x == 0) *flag = any;
}

// per-batch compaction: cidx[b][j] = j-th unmasked key, cnt[b] = {count, pad128}
__global__ __launch_bounds__(256) void compact_kernel(
    const void* __restrict__ mask, const int* __restrict__ flag,
    int* __restrict__ cidx, int* __restrict__ cnt)
{
  const int b = blockIdx.x;
  const int tid = threadIdx.x, lane = tid & 63, wave = tid >> 6;
  const bool u8m = (*flag != 0);
  const unsigned char* m8 = (const unsigned char*)mask + (long long)b * S_;
  const int* m32 = (const int*)mask + (long long)b * S_;

  int keep[8]; int my = 0;
#pragma unroll
  for (int j = 0; j < 8; ++j) {
    const int s = tid * 8 + j;
    const bool k = u8m ? (m8[s] == 0) : (m32[s] == 0);
    keep[j] = k ? 1 : 0; my += keep[j];
  }
  int pre = my;
#pragma unroll
  for (int o = 1; o < 64; o <<= 1) {
    const int n = __shfl_up(pre, o);
    if (lane >= o) pre += n;
  }
  __shared__ int wsum[4];
  if (lane == 63) wsum[wave] = pre;
  __syncthreads();
  int wbase = 0;
#pragma unroll
  for (int w = 0; w < 4; ++w) if (w < wave) wbase += wsum[w];
  int pos = wbase + pre - my;
  int* cx = cidx + (long long)b * S_;
#pragma unroll
  for (int j = 0; j < 8; ++j)
    if (keep[j]) cx[pos++] = tid * 8 + j;
  const int total = wsum[0] + wsum[1] + wsum[2] + wsum[3];
  const int cpad = (total + 127) & ~127;
  for (int i = total + tid; i < cpad; i += 256) cx[i] = 0;
  if (tid == 0) { cnt[b * 2] = total; cnt[b * 2 + 1] = cpad; }
}

// ---------------------------------------------------------------------------
extern "C" void kernel_launch(void* const* d_in, const int* in_sizes, int n_in,
                              void* d_out, int out_size, void* d_ws, size_t ws_size,
                              hipStream_t stream)
{
  const float* x    = (const float*)d_in[0];
  const void*  mask = d_in[1];
  const float* ln1w = (const float*)d_in[2];
  const float* ln1b = (const float*)d_in[3];
  const float* ln2w = (const float*)d_in[4];
  const float* ln2b = (const float*)d_in[5];
  const float* Wq   = (const float*)d_in[6];
  const float* bq   = (const float*)d_in[7];
  const float* Wk   = (const float*)d_in[8];
  const float* bk   = (const float*)d_in[9];
  const float* Wv   = (const float*)d_in[10];
  const float* bv   = (const float*)d_in[11];
  const float* W1   = (const float*)d_in[12];
  const float* b1   = (const float*)d_in[13];
  const float* W2   = (const float*)d_in[14];
  const float* b2   = (const float*)d_in[15];

  const size_t MB = 1024ull * 1024ull;
  char* p = (char*)d_ws;
  int* flag    = (int*)p;   p += 256;
  int* cnt     = (int*)p;   p += 256;
  int* cidx    = (int*)p;   p += (size_t)B_ * S_ * 4;
  u16* Wqb     = (u16*)p;   p += (size_t)E_ * E_ * 2;
  u16* Wkvb    = (u16*)p;   p += (size_t)2 * E_ * E_ * 2;   // [Wk;Wv]
  u16* W1b     = (u16*)p;   p += (size_t)2 * E_ * E_ * 2;
  u16* W2b     = (u16*)p;   p += (size_t)2 * E_ * E_ * 2;
  float* bkv   = (float*)p; p += 2 * E_ * 4;
  u16* normedb = (u16*)p;   p += (size_t)B_ * S_ * E_ * 2;
  char* chunk  = p;
  const size_t used  = (size_t)(p - (char*)d_ws);
  const size_t avail = (ws_size > used) ? (ws_size - used) : 0;

  // per-batch unit: Q [S,E] 4MB + KVc [S,2E] 8MB + Vt [E,S] 4MB + P 8MB = 24MB
  int bc = 1;
  for (int c = 8; c >= 1; c >>= 1)
    if (avail >= 24 * MB * (size_t)c) { bc = c; break; }

  float* out = (float*)d_out;
  dim3 blk(256);
  dim3 blkg(256);

  detect_kernel<<<1, 256, 0, stream>>>((const unsigned char*)mask, flag);
  compact_kernel<<<B_, blk, 0, stream>>>(mask, flag, cidx, cnt);
  {
    const long long tot = 7LL * E_ * E_ + 2 * E_;
    prep_kernel<<<(int)((tot + 255) / 256), blk, 0, stream>>>(
        Wq, Wk, Wv, W1, W2, bk, bv, Wqb, Wkvb, W1b, W2b, bkv);
  }

  layernorm_kernel<<<B_ * S_, blk, 0, stream>>>(x, ln1w, ln1b, normedb);

  for (int b0 = 0; b0 < B_; b0 += bc) {
    u16* Qc  = (u16*)chunk;                          // [bc*S][E]
    u16* KVc = Qc + (size_t)bc * S_ * E_;            // [bc][S][2E] (compact rows)
    u16* Vt  = KVc + (size_t)bc * S_ * 2 * E_;       // [bc][E][S]
    u16* Pc  = Vt + (size_t)bc * E_ * S_;            // [bc][S][S] scores->P
    const int* cntb  = cnt + b0 * 2;
    const int* cidxb = cidx + (size_t)b0 * S_;

    // Q = normed @ Wq^T + bq  (all rows, flat M = bc*S)
    gemm_nt<true, false, false, true, false, false, false>
        <<<dim3(E_ / 128, bc * S_ / 128, 1), blkg, 0, stream>>>(
        normedb + (size_t)b0 * S_ * E_, Wqb, Qc, bq, nullptr,
        E_, E_, E_, E_, 0, 0, 0, nullptr, nullptr);

    // KV_compact = normed[cidx] @ [Wk;Wv]^T + bkv  (z=bc, M early-out)
    gemm_nt<true, false, false, true, false, true, false>
        <<<dim3(2 * E_ / 128, S_ / 128, bc), blkg, 0, stream>>>(
        normedb + (size_t)b0 * S_ * E_, Wkvb, KVc, bkv, nullptr,
        E_, E_, 2 * E_, E_,
        (long long)S_ * E_, 0, (long long)S_ * 2 * E_, cidxb, cntb);

    // Vt = transpose of V slice (compact cols only)
    transpose_kernel<<<dim3(E_ / 32, S_ / 32, bc), blk, 0, stream>>>(KVc, Vt, cntb);

    // scores = (Q @ Kc^T)/32, col>=count -> -inf, bf16 (N early-out)
    gemm_nt<false, false, false, true, true, false, false>
        <<<dim3(S_ / 128, S_ / 128, bc), blkg, 0, stream>>>(
        Qc, KVc, Pc, nullptr, nullptr,
        E_, 2 * E_, S_, E_,
        (long long)S_ * E_, (long long)S_ * 2 * E_, (long long)S_ * S_,
        nullptr, cntb);

    // softmax in place over compact width
    softmax_bf16_kernel<<<bc * S_, blk, 0, stream>>>(Pc, cntb);

    // out = P @ Vt^T + x  (K = cnt_pad runtime)
    gemm_nt<false, false, true, false, false, false, true>
        <<<dim3(E_ / 128, S_ / 128, bc), blkg, 0, stream>>>(
        Pc, Vt, out + (size_t)b0 * S_ * E_, nullptr,
        x + (size_t)b0 * S_ * E_, S_, S_, E_, S_,
        (long long)S_ * S_, (long long)E_ * S_, (long long)S_ * E_,
        nullptr, cntb);
  }

  layernorm_kernel<<<B_ * S_, blk, 0, stream>>>(out, ln2w, ln2b, normedb);

  // FFN row-chunked: h[mr][2E] bf16 lives in the chunk region
  size_t mr_sz = avail / ((size_t)2 * E_ * 2);
  int mr = (int)((mr_sz > 16384) ? 16384 : mr_sz);
  mr &= ~127;
  if (mr < 128) mr = 128;
  u16* hb = (u16*)chunk;
  for (int m0 = 0; m0 < B_ * S_; m0 += mr) {
    const int mm = (B_ * S_ - m0 < mr) ? (B_ * S_ - m0) : mr;
    // h = relu(normed2 @ W1^T + b1)
    gemm_nt<true, true, false, true, false, false, false>
        <<<dim3((2 * E_) / 128, mm / 128, 1), blkg, 0, stream>>>(
        normedb + (size_t)m0 * E_, W1b, hb, b1, nullptr,
        E_, E_, 2 * E_, E_, 0, 0, 0, nullptr, nullptr);
    // out = h @ W2^T + b2 + out
    gemm_nt<true, false, true, false, false, false, false>
        <<<dim3(E_ / 128, mm / 128, 1), blkg, 0, stream>>>(
        hb, W2b, out + (size_t)m0 * E_, b2, out + (size_t)m0 * E_,
        2 * E_, 2 * E_, E_, 2 * E_, 0, 0, 0, nullptr, nullptr);
  }
}

// Round 9
// 624.220 us; speedup vs baseline: 1.1945x; 1.1945x over previous
//
#include <hip/hip_runtime.h>
#include <hip/hip_bf16.h>
#include <cstdint>

#define B_ 8
#define S_ 2048
#define E_ 1024

using u16 = unsigned short;

typedef __bf16 bf16x8 __attribute__((ext_vector_type(8)));
typedef float f32x4 __attribute__((ext_vector_type(4)));

__device__ inline u16 f2bf(float f) {
  uint32_t u = __float_as_uint(f);
  uint32_t r = (u + 0x7fffu + ((u >> 16) & 1u)) >> 16;
  return (u16)r;
}

// ---------------------------------------------------------------------------
// NT GEMM, r9: 256x256 tile, BK=64, 512 threads (8 waves 2x4), r6 skeleton
// with EVEN READ SPREAD (4/0/8/12 per phase) via cross-tile register carry:
//   ph1: read B1->bfv2(4) | BAR | lgkm(4) | 16 MFMA Q(0,0)(af,bfv) | lgkm(0) | BAR
//   ph2: stage B0,B1(t+2) | BAR | 16 MFMA Q(0,1)(af,bfv2) (no wait) | BAR
//   ph3: read A1->af(8) | stage A0(t+2) | BAR | lgkm(6/4/2/0)+MFMA Q(1,1) | BAR
//   ph4: 16 MFMA Q(1,0)(af,bfv) | sched_barrier | vmcnt(6) |
//        read NEXT tile A0->af(8), B0->bfv(4) from buf^1 | stage A1(t+2) | BAR
// vmcnt(6): outstanding = 6 own (t+2) loads -> all t+1 landed BEFORE the
// buf^1 reads. ph1's trailing lgkm(0)+BAR drains ALL DS chip-wide before
// ph2's B-stages overwrite B regions; ph3's lgkm(0)+BAR before ph4's A1
// stage; ph4's preloads drain at ph1(t+1) (per-wave lgkm(4), chip-wide by
// ph1-end BAR) before ph2(t+1)/ph3(t+1) stages. Post-loop lgkmcnt(0) drains
// the dead tail preloads before epilogue register reuse.
// VALU trim: per-tile t2/ko2 + LDS slot base computed once.
// T2 swizzle / XCD swizzle / asm ds_read / counted waits / setprio: as r6.
// ---------------------------------------------------------------------------
template<bool HAS_BIAS, bool RELU, bool HAS_RES, bool OUT_BF16, bool SCORES,
         bool GATHER_A, bool RUNTK>
__global__ __launch_bounds__(512, 2) void gemm_nt(
    const u16* __restrict__ A, const u16* __restrict__ B, void* __restrict__ C,
    const float* __restrict__ bias, const float* __restrict__ res,
    int lda, int ldb, int ldc, int K,
    long long strideA, long long strideB, long long strideC,
    const int* __restrict__ cidx, const int* __restrict__ cnt)
{
  // [buf][half][128 rows * 64 cols]
  __shared__ __attribute__((aligned(16))) u16 lA[2][2][128 * 64];
  __shared__ __attribute__((aligned(16))) u16 lB[2][2][128 * 64];

  const int tid  = threadIdx.x;
  const int lane = tid & 63;
  const int wave = tid >> 6;

  // ---- XCD-compacting block swizzle (GM=8, GN=4 so all 256-grids qualify) ----
  const int GM = 8, GN = 4;
  const int nbn = gridDim.x, nbm = gridDim.y, nz = gridDim.z;
  int bm, bn, bz;
  {
    const int total = nbn * nbm * nz;
    const long long lin = blockIdx.x +
        (long long)nbn * (blockIdx.y + (long long)nbm * blockIdx.z);
    if ((nbm % GM) == 0 && (nbn % GN) == 0 && (total % (8 * GM * GN)) == 0) {
      const int xcd = (int)(lin & 7);
      const int loc = (int)(lin >> 3);
      const int sper = GM * GN;
      const int super = (loc / sper) * 8 + xcd;
      const int ins   = loc % sper;
      const int spz = (nbm / GM) * (nbn / GN);
      bz = super / spz;
      const int s2 = super % spz;
      const int sm = s2 % (nbm / GM);
      const int sn = s2 / (nbm / GM);
      bm = sm * GM + (ins % GM);
      bn = sn * GN + (ins / GM);
    } else { bm = blockIdx.y; bn = blockIdx.x; bz = blockIdx.z; }
  }

  int count = 0, cpad = 0;
  if (SCORES || GATHER_A || RUNTK) {
    count = cnt[bz * 2];
    cpad  = cnt[bz * 2 + 1];               // 256-aligned
    if (GATHER_A && bm * 256 >= cpad) return;   // block-uniform, pre-barrier
    if (SCORES   && bn * 256 >= cpad) return;
  }
  const int Keff = RUNTK ? cpad : K;
  const int nk = Keff >> 6;                // K-tiles of 64 (>= 4 always)

  const u16* Ab = A + (long long)bz * strideA;
  const u16* Bb = B + (long long)bz * strideB;

  // ---- staging addresses (per thread: 2x16B per half-tile) ----
  const int srow = tid >> 3;               // 0..63 (+l*64)
  // inverse-swizzled SOURCE column (elements); (srow+l*64)&7 == srow&7
  const int scol = ((tid & 7) ^ (srow & 7)) * 8;
  long long rowA[2][2], rowB[2][2];        // [half][l] element offsets (no k)
#pragma unroll
  for (int h = 0; h < 2; ++h)
#pragma unroll
    for (int l = 0; l < 2; ++l) {
      int ra = bm * 256 + h * 128 + srow + l * 64;
      if (GATHER_A) ra = cidx[(long long)bz * S_ + ra];
      rowA[h][l] = (long long)ra * lda + scol;
      rowB[h][l] = (long long)(bn * 256 + h * 128 + srow + l * 64) * ldb + scol;
    }
  const int ldsoff0 = tid * 8;             // u16 elems within 8192-elem slot
  const int ldsoff1 = (tid + 512) * 8;

  // ---- fragment read addresses (swizzled, 32-bit LDS offsets for asm) ----
  const int wr = wave >> 2, wc = wave & 3;
  const int rA = wr * 64 + (lane & 15);    // row within A half-slot (+mi*16)
  const int rB = wc * 32 + (lane & 15);    // row within B half-slot (+ni*16)
#define LDSP3(P) ((uint32_t)(uintptr_t)(__attribute__((address_space(3))) const void*)(P))
  uint32_t aA0 = LDSP3(&lA[0][0][0]) +
      2u * (uint32_t)(rA * 64 + (((0 * 4 + (lane >> 4)) ^ (rA & 7)) * 8));
  uint32_t aA1 = LDSP3(&lA[0][0][0]) +
      2u * (uint32_t)(rA * 64 + (((1 * 4 + (lane >> 4)) ^ (rA & 7)) * 8));
  uint32_t bB0 = LDSP3(&lB[0][0][0]) +
      2u * (uint32_t)(rB * 64 + (((0 * 4 + (lane >> 4)) ^ (rB & 7)) * 8));
  uint32_t bB1 = LDSP3(&lB[0][0][0]) +
      2u * (uint32_t)(rB * 64 + (((1 * 4 + (lane >> 4)) ^ (rB & 7)) * 8));
#undef LDSP3

  f32x4 acc[2][2][4][2];                   // [mh][nh][mi][ni]
#pragma unroll
  for (int a = 0; a < 2; ++a)
#pragma unroll
    for (int b = 0; b < 2; ++b)
#pragma unroll
      for (int mi = 0; mi < 4; ++mi)
#pragma unroll
        for (int ni = 0; ni < 2; ++ni)
          acc[a][b][mi][ni] = (f32x4){0.f, 0.f, 0.f, 0.f};

// prologue-style stage (computes its own clamp; T always < nk in prologue)
#define STAGE_A(H, T) {                                                        \
    const int tt_ = ((T) < nk) ? (T) : (nk - 1);                               \
    __builtin_amdgcn_global_load_lds(                                          \
        (const __attribute__((address_space(1))) void*)                        \
            (Ab + rowA[H][0] + (long long)tt_ * 64),                           \
        (__attribute__((address_space(3))) void*)(&lA[(T) & 1][H][ldsoff0]),   \
        16, 0, 0);                                                             \
    __builtin_amdgcn_global_load_lds(                                          \
        (const __attribute__((address_space(1))) void*)                        \
            (Ab + rowA[H][1] + (long long)tt_ * 64),                           \
        (__attribute__((address_space(3))) void*)(&lA[(T) & 1][H][ldsoff1]),   \
        16, 0, 0); }

#define STAGE_B(H, T) {                                                        \
    const int tt_ = ((T) < nk) ? (T) : (nk - 1);                               \
    __builtin_amdgcn_global_load_lds(                                          \
        (const __attribute__((address_space(1))) void*)                        \
            (Bb + rowB[H][0] + (long long)tt_ * 64),                           \
        (__attribute__((address_space(3))) void*)(&lB[(T) & 1][H][ldsoff0]),   \
        16, 0, 0);                                                             \
    __builtin_amdgcn_global_load_lds(                                          \
        (const __attribute__((address_space(1))) void*)                        \
            (Bb + rowB[H][1] + (long long)tt_ * 64),                           \
        (__attribute__((address_space(3))) void*)(&lB[(T) & 1][H][ldsoff1]),   \
        16, 0, 0); }

// loop-stage: precomputed k-offset ko2, slot base lAb/lBb ((t+2)&1 == t&1)
#define STAGE_A2(H) {                                                          \
    __builtin_amdgcn_global_load_lds(                                          \
        (const __attribute__((address_space(1))) void*)(Ab + rowA[H][0] + ko2),\
        (__attribute__((address_space(3))) void*)(lAb + (H) * 8192 + ldsoff0), \
        16, 0, 0);                                                             \
    __builtin_amdgcn_global_load_lds(                                          \
        (const __attribute__((address_space(1))) void*)(Ab + rowA[H][1] + ko2),\
        (__attribute__((address_space(3))) void*)(lAb + (H) * 8192 + ldsoff1), \
        16, 0, 0); }

#define STAGE_B2(H) {                                                          \
    __builtin_amdgcn_global_load_lds(                                          \
        (const __attribute__((address_space(1))) void*)(Bb + rowB[H][0] + ko2),\
        (__attribute__((address_space(3))) void*)(lBb + (H) * 8192 + ldsoff0), \
        16, 0, 0);                                                             \
    __builtin_amdgcn_global_load_lds(                                          \
        (const __attribute__((address_space(1))) void*)(Bb + rowB[H][1] + ko2),\
        (__attribute__((address_space(3))) void*)(lBb + (H) * 8192 + ldsoff1), \
        16, 0, 0); }

#define DSR(D, ADDR, OFF) \
    asm volatile("ds_read_b128 %0, %1 offset:" OFF : "=v"(D) : "v"(ADDR))
#define LGKM(NSTR) asm volatile("s_waitcnt lgkmcnt(" NSTR ")" ::: "memory")
#define SCHED0()   __builtin_amdgcn_sched_barrier(0)
#define BAR()      __builtin_amdgcn_s_barrier()

// 4 MFMAs for one mi row of a quadrant (BF = bfv or bfv2)
#define MFMA_MI(MH, NH, MI, BF) {                                              \
    _Pragma("unroll") for (int ni = 0; ni < 2; ++ni)                           \
      _Pragma("unroll") for (int k2 = 0; k2 < 2; ++k2)                         \
        acc[MH][NH][MI][ni] = __builtin_amdgcn_mfma_f32_16x16x32_bf16(         \
            af[MI][k2], BF[ni][k2], acc[MH][NH][MI][ni], 0, 0, 0); }

  // ---- prologue: stage tiles 0 and 1 fully (16 loads); vmcnt(8) = tile0 in --
  STAGE_A(0, 0); STAGE_B(0, 0); STAGE_B(1, 0); STAGE_A(1, 0);
  STAGE_B(0, 1); STAGE_B(1, 1); STAGE_A(0, 1); STAGE_A(1, 1);
  asm volatile("s_waitcnt vmcnt(8)" ::: "memory");   // tile0 fully landed
  BAR();

  bf16x8 af[4][2], bfv[2][2], bfv2[2][2];
  // preload tile0: A0 -> af, B0 -> bfv (waited by ph1's lgkm(4))
  DSR(af[0][0], aA0, "0");     DSR(af[0][1], aA1, "0");
  DSR(af[1][0], aA0, "2048");  DSR(af[1][1], aA1, "2048");
  DSR(af[2][0], aA0, "4096");  DSR(af[2][1], aA1, "4096");
  DSR(af[3][0], aA0, "6144");  DSR(af[3][1], aA1, "6144");
  DSR(bfv[0][0], bB0, "0");    DSR(bfv[0][1], bB1, "0");
  DSR(bfv[1][0], bB0, "2048"); DSR(bfv[1][1], bB1, "2048");

  for (int t = 0; t < nk; ++t) {
    const int t2 = (t + 2 < nk) ? (t + 2) : (nk - 1);
    const long long ko2 = (long long)t2 * 64;
    u16* lAb = &lA[t & 1][0][0];
    u16* lBb = &lB[t & 1][0][0];
    // ---- ph1: Q(0,0) af(A0) x bfv(B0) | read B1->bfv2 ----
    DSR(bfv2[0][0], bB0, "16384"); DSR(bfv2[0][1], bB1, "16384");
    DSR(bfv2[1][0], bB0, "18432"); DSR(bfv2[1][1], bB1, "18432");
    BAR();
    __builtin_amdgcn_s_setprio(1);
    LGKM("4"); SCHED0();                   // af+bfv (oldest 12 of 16) done
    MFMA_MI(0, 0, 0, bfv); MFMA_MI(0, 0, 1, bfv);
    MFMA_MI(0, 0, 2, bfv); MFMA_MI(0, 0, 3, bfv);
    __builtin_amdgcn_s_setprio(0);
    LGKM("0");                             // drain bfv2: all DS done pre-BAR
    BAR();
    // ---- ph2: Q(0,1) af(A0) x bfv2(B1) | stage B0,B1(t+2) ----
    STAGE_B2(0); STAGE_B2(1);
    BAR();
    __builtin_amdgcn_s_setprio(1);
    MFMA_MI(0, 1, 0, bfv2); MFMA_MI(0, 1, 1, bfv2);
    MFMA_MI(0, 1, 2, bfv2); MFMA_MI(0, 1, 3, bfv2);
    __builtin_amdgcn_s_setprio(0);
    BAR();
    // ---- ph3: Q(1,1) af(A1) x bfv2(B1) | read A1->af | stage A0(t+2) ----
    DSR(af[0][0], aA0, "16384"); DSR(af[0][1], aA1, "16384");
    DSR(af[1][0], aA0, "18432"); DSR(af[1][1], aA1, "18432");
    DSR(af[2][0], aA0, "20480"); DSR(af[2][1], aA1, "20480");
    DSR(af[3][0], aA0, "22528"); DSR(af[3][1], aA1, "22528");
    STAGE_A2(0);
    BAR();
    __builtin_amdgcn_s_setprio(1);
    LGKM("6"); SCHED0(); MFMA_MI(1, 1, 0, bfv2);
    LGKM("4"); SCHED0(); MFMA_MI(1, 1, 1, bfv2);
    LGKM("2"); SCHED0(); MFMA_MI(1, 1, 2, bfv2);
    LGKM("0"); SCHED0(); MFMA_MI(1, 1, 3, bfv2);
    __builtin_amdgcn_s_setprio(0);
    BAR();
    // ---- ph4: Q(1,0) af(A1) x bfv(B0) | vmcnt(6) | preload next A0,B0 ----
    __builtin_amdgcn_s_setprio(1);
    MFMA_MI(1, 0, 0, bfv); MFMA_MI(1, 0, 1, bfv);
    MFMA_MI(1, 0, 2, bfv); MFMA_MI(1, 0, 3, bfv);
    __builtin_amdgcn_s_setprio(0);
    SCHED0();                              // pin MFMA before reg overwrite
    asm volatile("s_waitcnt vmcnt(6)" ::: "memory");  // tile t+1 fully landed
    {
      const uint32_t ad = (t & 1) ? (uint32_t)-32768 : 32768u;
      const uint32_t aA0n = aA0 + ad, aA1n = aA1 + ad;
      const uint32_t bB0n = bB0 + ad, bB1n = bB1 + ad;
      DSR(af[0][0], aA0n, "0");     DSR(af[0][1], aA1n, "0");
      DSR(af[1][0], aA0n, "2048");  DSR(af[1][1], aA1n, "2048");
      DSR(af[2][0], aA0n, "4096");  DSR(af[2][1], aA1n, "4096");
      DSR(af[3][0], aA0n, "6144");  DSR(af[3][1], aA1n, "6144");
      DSR(bfv[0][0], bB0n, "0");    DSR(bfv[0][1], bB1n, "0");
      DSR(bfv[1][0], bB0n, "2048"); DSR(bfv[1][1], bB1n, "2048");
      STAGE_A2(1);
      BAR();
      aA0 = aA0n; aA1 = aA1n; bB0 = bB0n; bB1 = bB1n;
    }
  }
  // drain dummy stages AND the dead tail preloads before reusing registers
  asm volatile("s_waitcnt vmcnt(0) lgkmcnt(0)" ::: "memory");

#undef MFMA_MI
#undef DSR
#undef STAGE_A
#undef STAGE_B
#undef STAGE_A2
#undef STAGE_B2
#undef BAR
#undef LGKM
#undef SCHED0

  // ---- epilogue: C/D layout col = lane&15, row = (lane>>4)*4 + reg ----
  const float* resb = (const float*)C;
  if (HAS_RES) resb = res + (long long)bz * strideC;
  u16*   cb16 = (u16*)C   + (long long)bz * strideC;
  float* cf32 = (float*)C + (long long)bz * strideC;

#pragma unroll
  for (int mh = 0; mh < 2; ++mh)
#pragma unroll
  for (int nh = 0; nh < 2; ++nh)
#pragma unroll
  for (int ni = 0; ni < 2; ++ni) {
    const int gn = bn * 256 + nh * 128 + wc * 32 + ni * 16 + (lane & 15);
    const float bvv = HAS_BIAS ? bias[gn] : 0.f;
    const bool cmask = SCORES && (gn >= count);
#pragma unroll
    for (int mi = 0; mi < 4; ++mi) {
#pragma unroll
      for (int r = 0; r < 4; ++r) {
        const int gm = bm * 256 + mh * 128 + wr * 64 + mi * 16 + (lane >> 4) * 4 + r;
        const long long idx = (long long)gm * ldc + gn;
        float v = acc[mh][nh][mi][ni][r] + bvv;
        if (SCORES) { v *= 0.03125f; if (cmask) v = -3.0e38f; }
        if (RELU) v = fmaxf(v, 0.f);
        if (HAS_RES) v += resb[idx];
        if (OUT_BF16) cb16[idx] = f2bf(v);
        else          cf32[idx] = v;
      }
    }
  }
}

// ---------------------------------------------------------------------------
__global__ __launch_bounds__(256) void layernorm_kernel(
    const float* __restrict__ x, const float* __restrict__ w,
    const float* __restrict__ b, u16* __restrict__ out)
{
  const int row = blockIdx.x;
  const int tid = threadIdx.x;
  const float4 v = ((const float4*)(x + (long long)row * E_))[tid];
  float s  = v.x + v.y + v.z + v.w;
  float s2 = v.x * v.x + v.y * v.y + v.z * v.z + v.w * v.w;
#pragma unroll
  for (int o = 32; o >= 1; o >>= 1) { s += __shfl_xor(s, o); s2 += __shfl_xor(s2, o); }
  __shared__ float rs[4], rs2[4];
  const int wave = tid >> 6, lane = tid & 63;
  if (lane == 0) { rs[wave] = s; rs2[wave] = s2; }
  __syncthreads();
  s  = rs[0] + rs[1] + rs[2] + rs[3];
  s2 = rs2[0] + rs2[1] + rs2[2] + rs2[3];
  const float mu   = s * (1.f / E_);
  const float var  = s2 * (1.f / E_) - mu * mu;
  const float rstd = rsqrtf(var + 1e-5f);
  const float4 wv = ((const float4*)w)[tid];
  const float4 bv = ((const float4*)b)[tid];
  ushort4 o;
  o.x = f2bf((v.x - mu) * rstd * wv.x + bv.x);
  o.y = f2bf((v.y - mu) * rstd * wv.y + bv.y);
  o.z = f2bf((v.z - mu) * rstd * wv.z + bv.z);
  o.w = f2bf((v.w - mu) * rstd * wv.w + bv.w);
  ((ushort4*)(out + (long long)row * E_))[tid] = o;
}

// ---------------------------------------------------------------------------
// in-place softmax over one bf16 row; only cols < cnt_pad touched
__global__ __launch_bounds__(256) void softmax_bf16_kernel(
    u16* __restrict__ sp, const int* __restrict__ cnt)
{
  const int row = blockIdx.x;
  const int bz  = row >> 11;            // row / S_
  const int tid = threadIdx.x;
  const int cpad = cnt[bz * 2 + 1];
  const bool act = (tid * 8) < cpad;
  u16* pr = sp + (long long)row * S_;

  float v[8];
  if (act) {
    const uint4 raw = ((const uint4*)pr)[tid];
    const uint32_t w[4] = {raw.x, raw.y, raw.z, raw.w};
#pragma unroll
    for (int c = 0; c < 4; ++c) {
      v[2 * c]     = __uint_as_float(w[c] << 16);
      v[2 * c + 1] = __uint_as_float(w[c] & 0xffff0000u);
    }
  } else {
#pragma unroll
    for (int i = 0; i < 8; ++i) v[i] = -3.38e38f;
  }
  float mx = -3.38e38f;
#pragma unroll
  for (int i = 0; i < 8; ++i) mx = fmaxf(mx, v[i]);
#pragma unroll
  for (int o = 32; o >= 1; o >>= 1) mx = fmaxf(mx, __shfl_xor(mx, o));
  __shared__ float red[4];
  const int wave = tid >> 6, lane = tid & 63;
  if (lane == 0) red[wave] = mx;
  __syncthreads();
  mx = fmaxf(fmaxf(red[0], red[1]), fmaxf(red[2], red[3]));

  float s = 0.f;
#pragma unroll
  for (int i = 0; i < 8; ++i) { v[i] = __expf(v[i] - mx); s += v[i]; }
#pragma unroll
  for (int o = 32; o >= 1; o >>= 1) s += __shfl_xor(s, o);
  __syncthreads();
  if (lane == 0) red[wave] = s;
  __syncthreads();
  s = red[0] + red[1] + red[2] + red[3];
  const float inv = 1.f / s;

  if (act) {
    uint4 o4;
    uint32_t* ow = (uint32_t*)&o4;
#pragma unroll
    for (int c = 0; c < 4; ++c) {
      const uint32_t lo = f2bf(v[2 * c] * inv);
      const uint32_t hi = f2bf(v[2 * c + 1] * inv);
      ow[c] = lo | (hi << 16);
    }
    ((uint4*)pr)[tid] = o4;
  }
}

// ---------------------------------------------------------------------------
// V slice of KVc [bc][S_,2E] (cols [E,2E)) -> Vt [bc][E][S_], early-out > cpad
__global__ __launch_bounds__(256) void transpose_kernel(
    const u16* __restrict__ KVc, u16* __restrict__ Vt, const int* __restrict__ cnt)
{
  const int bl = blockIdx.z;
  const int s0 = blockIdx.y * 32;
  if (s0 >= cnt[bl * 2 + 1]) return;
  __shared__ u16 tile[32][33];
  const int e0 = blockIdx.x * 32;
  const int tx = threadIdx.x & 31, ty = threadIdx.x >> 5;   // ty 0..7
  const u16* src = KVc + ((long long)bl * S_ + s0) * (2 * E_) + E_ + e0;
#pragma unroll
  for (int r = 0; r < 32; r += 8)
    tile[ty + r][tx] = src[(long long)(ty + r) * (2 * E_) + tx];
  __syncthreads();
  u16* dst = Vt + ((long long)bl * E_ + e0) * S_ + s0;
#pragma unroll
  for (int r = 0; r < 32; r += 8)
    dst[(long long)(ty + r) * S_ + tx] = tile[tx][ty + r];
}

// ---------------------------------------------------------------------------
// fused weight converts + bias concat
__global__ __launch_bounds__(256) void prep_kernel(
    const float* __restrict__ Wq, const float* __restrict__ Wk,
    const float* __restrict__ Wv, const float* __restrict__ W1,
    const float* __restrict__ W2, const float* __restrict__ bk,
    const float* __restrict__ bv,
    u16* __restrict__ Wqb, u16* __restrict__ Wkvb,
    u16* __restrict__ W1b, u16* __restrict__ W2b, float* __restrict__ bkv)
{
  const int N1 = E_ * E_;
  const long long i = (long long)blockIdx.x * 256 + threadIdx.x;
  if (i < N1)               Wqb[i] = f2bf(Wq[i]);
  else if (i < 2LL * N1)    Wkvb[i - N1] = f2bf(Wk[i - N1]);
  else if (i < 3LL * N1)    Wkvb[N1 + (i - 2LL * N1)] = f2bf(Wv[i - 2LL * N1]);
  else if (i < 5LL * N1)    W1b[i - 3LL * N1] = f2bf(W1[i - 3LL * N1]);
  else if (i < 7LL * N1)    W2b[i - 5LL * N1] = f2bf(W2[i - 5LL * N1]);
  else if (i < 7LL * N1 + 2 * E_) {
    const int j = (int)(i - 7LL * N1);
    bkv[j] = (j < E_) ? bk[j] : bv[j - E_];
  }
}

// Detect pad_mask storage: int32 0/1 has zero bytes at i%4!=0; u8 does not.
__global__ void detect_kernel(const unsigned char* __restrict__ m, int* __restrict__ flag)
{
  __shared__ int any;
  if (threadIdx.x == 0) any = 0;
  __syncthreads();
  int loc = 0;
  for (int i = threadIdx.x; i < B_ * S_; i += 256)
    if ((i & 3) && m[i]) loc = 1;
  if (loc) atomicOr(&any, 1);
  __syncthreads();
  if (threadIdx.x == 0) *flag = any;
}

// per-batch compaction: cidx[b][j] = j-th unmasked key, cnt[b] = {count, pad256}
__global__ __launch_bounds__(256) void compact_kernel(
    const void* __restrict__ mask, const int* __restrict__ flag,
    int* __restrict__ cidx, int* __restrict__ cnt)
{
  const int b = blockIdx.x;
  const int tid = threadIdx.x, lane = tid & 63, wave = tid >> 6;
  const bool u8m = (*flag != 0);
  const unsigned char* m8 = (const unsigned char*)mask + (long long)b * S_;
  const int* m32 = (const int*)mask + (long long)b * S_;

  int keep[8]; int my = 0;
#pragma unroll
  for (int j = 0; j < 8; ++j) {
    const int s = tid * 8 + j;
    const bool k = u8m ? (m8[s] == 0) : (m32[s] == 0);
    keep[j] = k ? 1 : 0; my += keep[j];
  }
  int pre = my;
#pragma unroll
  for (int o = 1; o < 64; o <<= 1) {
    const int n = __shfl_up(pre, o);
    if (lane >= o) pre += n;
  }
  __shared__ int wsum[4];
  if (lane == 63) wsum[wave] = pre;
  __syncthreads();
  int wbase = 0;
#pragma unroll
  for (int w = 0; w < 4; ++w) if (w < wave) wbase += wsum[w];
  int pos = wbase + pre - my;
  int* cx = cidx + (long long)b * S_;
#pragma unroll
  for (int j = 0; j < 8; ++j)
    if (keep[j]) cx[pos++] = tid * 8 + j;
  const int total = wsum[0] + wsum[1] + wsum[2] + wsum[3];
  const int cpad = (total + 255) & ~255;
  for (int i = total + tid; i < cpad; i += 256) cx[i] = 0;
  if (tid == 0) { cnt[b * 2] = total; cnt[b * 2 + 1] = cpad; }
}

// ---------------------------------------------------------------------------
extern "C" void kernel_launch(void* const* d_in, const int* in_sizes, int n_in,
                              void* d_out, int out_size, void* d_ws, size_t ws_size,
                              hipStream_t stream)
{
  const float* x    = (const float*)d_in[0];
  const void*  mask = d_in[1];
  const float* ln1w = (const float*)d_in[2];
  const float* ln1b = (const float*)d_in[3];
  const float* ln2w = (const float*)d_in[4];
  const float* ln2b = (const float*)d_in[5];
  const float* Wq   = (const float*)d_in[6];
  const float* bq   = (const float*)d_in[7];
  const float* Wk   = (const float*)d_in[8];
  const float* bk   = (const float*)d_in[9];
  const float* Wv   = (const float*)d_in[10];
  const float* bv   = (const float*)d_in[11];
  const float* W1   = (const float*)d_in[12];
  const float* b1   = (const float*)d_in[13];
  const float* W2   = (const float*)d_in[14];
  const float* b2   = (const float*)d_in[15];

  const size_t MB = 1024ull * 1024ull;
  char* p = (char*)d_ws;
  int* flag    = (int*)p;   p += 256;
  int* cnt     = (int*)p;   p += 256;
  int* cidx    = (int*)p;   p += (size_t)B_ * S_ * 4;
  u16* Wqb     = (u16*)p;   p += (size_t)E_ * E_ * 2;
  u16* Wkvb    = (u16*)p;   p += (size_t)2 * E_ * E_ * 2;   // [Wk;Wv]
  u16* W1b     = (u16*)p;   p += (size_t)2 * E_ * E_ * 2;
  u16* W2b     = (u16*)p;   p += (size_t)2 * E_ * E_ * 2;
  float* bkv   = (float*)p; p += 2 * E_ * 4;
  u16* normedb = (u16*)p;   p += (size_t)B_ * S_ * E_ * 2;
  char* chunk  = p;
  const size_t used  = (size_t)(p - (char*)d_ws);
  const size_t avail = (ws_size > used) ? (ws_size - used) : 0;

  // per-batch unit: Q [S,E] 4MB + KVc [S,2E] 8MB + Vt [E,S] 4MB + P 8MB = 24MB
  int bc = 1;
  for (int c = 8; c >= 1; c >>= 1)
    if (avail >= 24 * MB * (size_t)c) { bc = c; break; }

  float* out = (float*)d_out;
  dim3 blk(256);
  dim3 blkg(512);

  detect_kernel<<<1, 256, 0, stream>>>((const unsigned char*)mask, flag);
  compact_kernel<<<B_, blk, 0, stream>>>(mask, flag, cidx, cnt);
  {
    const long long tot = 7LL * E_ * E_ + 2 * E_;
    prep_kernel<<<(int)((tot + 255) / 256), blk, 0, stream>>>(
        Wq, Wk, Wv, W1, W2, bk, bv, Wqb, Wkvb, W1b, W2b, bkv);
  }

  layernorm_kernel<<<B_ * S_, blk, 0, stream>>>(x, ln1w, ln1b, normedb);

  for (int b0 = 0; b0 < B_; b0 += bc) {
    u16* Qc  = (u16*)chunk;                          // [bc*S][E]
    u16* KVc = Qc + (size_t)bc * S_ * E_;            // [bc][S][2E] (compact rows)
    u16* Vt  = KVc + (size_t)bc * S_ * 2 * E_;       // [bc][E][S]
    u16* Pc  = Vt + (size_t)bc * E_ * S_;            // [bc][S][S] scores->P
    const int* cntb  = cnt + b0 * 2;
    const int* cidxb = cidx + (size_t)b0 * S_;

    // Q = normed @ Wq^T + bq  (all rows, flat M = bc*S)
    gemm_nt<true, false, false, true, false, false, false>
        <<<dim3(E_ / 256, bc * S_ / 256, 1), blkg, 0, stream>>>(
        normedb + (size_t)b0 * S_ * E_, Wqb, Qc, bq, nullptr,
        E_, E_, E_, E_, 0, 0, 0, nullptr, nullptr);

    // KV_compact = normed[cidx] @ [Wk;Wv]^T + bkv  (z=bc, M early-out)
    gemm_nt<true, false, false, true, false, true, false>
        <<<dim3(2 * E_ / 256, S_ / 256, bc), blkg, 0, stream>>>(
        normedb + (size_t)b0 * S_ * E_, Wkvb, KVc, bkv, nullptr,
        E_, E_, 2 * E_, E_,
        (long long)S_ * E_, 0, (long long)S_ * 2 * E_, cidxb, cntb);

    // Vt = transpose of V slice (compact cols only)
    transpose_kernel<<<dim3(E_ / 32, S_ / 32, bc), blk, 0, stream>>>(KVc, Vt, cntb);

    // scores = (Q @ Kc^T)/32, col>=count -> -inf, bf16 (N early-out)
    gemm_nt<false, false, false, true, true, false, false>
        <<<dim3(S_ / 256, S_ / 256, bc), blkg, 0, stream>>>(
        Qc, KVc, Pc, nullptr, nullptr,
        E_, 2 * E_, S_, E_,
        (long long)S_ * E_, (long long)S_ * 2 * E_, (long long)S_ * S_,
        nullptr, cntb);

    // softmax in place over compact width
    softmax_bf16_kernel<<<bc * S_, blk, 0, stream>>>(Pc, cntb);

    // out = P @ Vt^T + x  (K = cnt_pad runtime)
    gemm_nt<false, false, true, false, false, false, true>
        <<<dim3(E_ / 256, S_ / 256, bc), blkg, 0, stream>>>(
        Pc, Vt, out + (size_t)b0 * S_ * E_, nullptr,
        x + (size_t)b0 * S_ * E_, S_, S_, E_, S_,
        (long long)S_ * S_, (long long)E_ * S_, (long long)S_ * E_,
        nullptr, cntb);
  }

  layernorm_kernel<<<B_ * S_, blk, 0, stream>>>(out, ln2w, ln2b, normedb);

  // FFN row-chunked: h[mr][2E] bf16 lives in the chunk region
  size_t mr_sz = avail / ((size_t)2 * E_ * 2);
  int mr = (int)((mr_sz > 16384) ? 16384 : mr_sz);
  mr &= ~255;
  if (mr < 256) mr = 256;
  u16* hb = (u16*)chunk;
  for (int m0 = 0; m0 < B_ * S_; m0 += mr) {
    const int mm = (B_ * S_ - m0 < mr) ? (B_ * S_ - m0) : mr;
    // h = relu(normed2 @ W1^T + b1)
    gemm_nt<true, true, false, true, false, false, false>
        <<<dim3((2 * E_) / 256, mm / 256, 1), blkg, 0, stream>>>(
        normedb + (size_t)m0 * E_, W1b, hb, b1, nullptr,
        E_, E_, 2 * E_, E_, 0, 0, 0, nullptr, nullptr);
    // out = h @ W2^T + b2 + out
    gemm_nt<true, false, true, false, false, false, false>
        <<<dim3(E_ / 256, mm / 256, 1), blkg, 0, stream>>>(
        hb, W2b, out + (size_t)m0 * E_, b2, out + (size_t)m0 * E_,
        2 * E_, 2 * E_, E_, 2 * E_, 0, 0, 0, nullptr, nullptr);
  }
}